// Round 8
// baseline (140.820 us; speedup 1.0000x reference)
//
#include <hip/hip_runtime.h>
#include <stdint.h>

#define NS_ 4096
#define M_  8192
#define D_  256
#define TEMP 0.07f
#define EXP_SCALE 20.61707212818536f   // log2(e)/0.07 : exp(sim/T) = exp2(sim*EXP_SCALE)
#define LN2 0.6931471805599453f

typedef short bf16x8 __attribute__((ext_vector_type(8)));
typedef float f32x4  __attribute__((ext_vector_type(4)));
typedef unsigned short ushortx4 __attribute__((ext_vector_type(4)));

static __device__ inline unsigned short f2bf(float x) {
    unsigned u = __float_as_uint(x);
    u += 0x7fffu + ((u >> 16) & 1u);
    return (unsigned short)(u >> 16);
}

static __device__ inline float cleanf(float v) {
    return __builtin_isfinite(v) ? v : 0.0f;
}

// ---------------- Kernel 1: clean + normalize -> bf16 F, fp32 pos[]; zero denom/cnt/out -
// grid = NS_/4, block = 256 (one wave per paired row; 4 row-pairs per block)
__global__ __launch_bounds__(256) void knorm(const float* __restrict__ z1,
                                             const float* __restrict__ z2,
                                             short* __restrict__ F,
                                             float* __restrict__ pos,
                                             float* __restrict__ denom,
                                             int* __restrict__ cnt,
                                             float* __restrict__ out) {
    const int wave = threadIdx.x >> 6;
    const int t    = threadIdx.x & 63;
    const int i    = blockIdx.x * 4 + wave;
    const float4* p1 = (const float4*)(z1 + (size_t)i * D_);
    const float4* p2 = (const float4*)(z2 + (size_t)i * D_);
    float4 a = p1[t], b = p2[t];
    a.x = cleanf(a.x); a.y = cleanf(a.y); a.z = cleanf(a.z); a.w = cleanf(a.w);
    b.x = cleanf(b.x); b.y = cleanf(b.y); b.z = cleanf(b.z); b.w = cleanf(b.w);

    float s1 = a.x*a.x + a.y*a.y + a.z*a.z + a.w*a.w;
    float s2 = b.x*b.x + b.y*b.y + b.z*b.z + b.w*b.w;
    float dp = a.x*b.x + a.y*b.y + a.z*b.z + a.w*b.w;
    #pragma unroll
    for (int m = 1; m < 64; m <<= 1) {
        s1 += __shfl_xor(s1, m);
        s2 += __shfl_xor(s2, m);
        dp += __shfl_xor(dp, m);
    }
    const float inv1 = 1.0f / fmaxf(sqrtf(s1), 1e-12f);
    const float inv2 = 1.0f / fmaxf(sqrtf(s2), 1e-12f);

    ushortx4 o1, o2;
    o1.x = f2bf(a.x * inv1); o1.y = f2bf(a.y * inv1); o1.z = f2bf(a.z * inv1); o1.w = f2bf(a.w * inv1);
    o2.x = f2bf(b.x * inv2); o2.y = f2bf(b.y * inv2); o2.z = f2bf(b.z * inv2); o2.w = f2bf(b.w * inv2);
    ((ushortx4*)(F + (size_t)i * D_))[t]          = o1;
    ((ushortx4*)(F + (size_t)(i + NS_) * D_))[t]  = o2;

    if (t == 0) pos[i] = dp * inv1 * inv2;       // exact fp32 positive sim
    if (t < 2)  denom[i * 2 + t] = 0.0f;         // zero denom (2 per row-pair x 4096)
    if (i == 0 && t < 32) cnt[t] = 0;            // zero rtile counters
    if (i == 0 && t == 0) out[0] = 0.0f;         // zero loss accumulator
}

// ---------------- Kernel 2: NO-LDS fused sim-GEMM + row exp-sums + finishers ------------
// F is 4 MB total == one XCD's L2 (and each block's B working set streams through L1):
// LDS staging of L2-resident data was pure overhead (Common-mistake #7 / m169). This
// version has NO LDS and NO barriers in the main loop: A-frags (128 VGPR) and B-frags
// are loaded DIRECTLY from global in the exact MFMA fragment layout (quad-lanes form
// 64B contiguous segments; pattern verified in R4, absmax 0.0). B double-buffered in
// registers (b0/b1, static names), loads issued one compute-block ahead so L1/L2 hit
// latency (~150-250 cyc) hides under the 32-MFMA block (~310 cyc across 2 waves/SIMD).
// Waves run fully decoupled — the all-waves-barrier-drain stall of R0..R7 is gone.
// grid = 512 = 32 rtiles x 16 col-blocks (256x512 tile, proven L2-healthy blocking).
// Epilogue + finisher byte-identical to R0.
__global__ __launch_bounds__(256, 2) void kgemm(const short* __restrict__ F,
                                                float* __restrict__ denom,
                                                int* __restrict__ cnt,
                                                const float* __restrict__ pos,
                                                float* __restrict__ out) {
    __shared__ int lastflag;
    __shared__ float red[4];

    const int rtile = blockIdx.x >> 4;   // 32 rtiles
    const int cq    = blockIdx.x & 15;   // 16 col-blocks
    const int R0 = rtile * 256;
    const int C0 = cq * 512;

    const int tid  = threadIdx.x;
    const int lane = tid & 63;
    const int wave = tid >> 6;
    const int c16  = lane & 15;
    const int quad = lane >> 4;

    // ---- A-frags: direct global loads, resident for the whole kernel (128 VGPR).
    // Lane (c16,quad) holds row R0+ch*64+wave*16+c16, k-chunk (ks*4+quad)*8 — the
    // 4 quad-lanes form one 64B contiguous segment per (row,ks).
    bf16x8 afrag[4][8];
    #pragma unroll
    for (int ch = 0; ch < 4; ++ch) {
        const short* ga = F + (size_t)(R0 + ch * 64 + wave * 16 + c16) * D_ + quad * 8;
        #pragma unroll
        for (int ks = 0; ks < 8; ++ks)
            afrag[ch][ks] = *(const bf16x8*)(ga + ks * 32);
    }

    float accexp[4][4];
    #pragma unroll
    for (int s = 0; s < 4; ++s)
        #pragma unroll
        for (int r = 0; r < 4; ++r) accexp[s][r] = 0.0f;

    // per-lane B base: column group g covers cols C0+g*16..+15; lane reads row
    // C0+g*16+c16, k-chunk (ks*4+quad)*8  (= quad*8 + ks*32 shorts from row start)
    const short* gbl = F + (size_t)(C0 + c16) * D_ + quad * 8;

    auto loadB = [&](int g, bf16x8* bf) {
        const short* gb = gbl + (size_t)g * (16 * D_);
        #pragma unroll
        for (int ks = 0; ks < 8; ++ks)
            bf[ks] = *(const bf16x8*)(gb + ks * 32);
    };

    auto computeB = [&](int g, const bf16x8* bf) {
        f32x4 acc[4];
        #pragma unroll
        for (int s = 0; s < 4; ++s) acc[s] = (f32x4){0.f, 0.f, 0.f, 0.f};
        #pragma unroll
        for (int ks = 0; ks < 8; ++ks)
            #pragma unroll
            for (int s = 0; s < 4; ++s)
                acc[s] = __builtin_amdgcn_mfma_f32_16x16x32_bf16(
                    afrag[s][ks], bf[ks], acc[s], 0, 0, 0);

        const int colbase = C0 + g * 16;
        #pragma unroll
        for (int s = 0; s < 4; ++s) {
            const int rowbase = R0 + s * 64 + wave * 16;
            if (colbase != rowbase) {            // uniform fast path
                #pragma unroll
                for (int r = 0; r < 4; ++r)
                    accexp[s][r] += __builtin_amdgcn_exp2f(acc[s][r] * EXP_SCALE);
            } else {                             // diagonal 16x16 tile: zero self-pairs
                #pragma unroll
                for (int r = 0; r < 4; ++r) {
                    float e = __builtin_amdgcn_exp2f(acc[s][r] * EXP_SCALE);
                    if (c16 == quad * 4 + r) e = 0.0f;
                    accexp[s][r] += e;
                }
            }
        }
    };

    // ---- main loop: 32 column groups of 16, register double-buffer, 1-ahead prefetch
    bf16x8 b0[8], b1[8];
    loadB(0, b0);
    for (int g = 0; g < 32; g += 2) {
        loadB(g + 1, b1);          // in flight while computing g
        computeB(g, b0);
        if (g + 2 < 32) loadB(g + 2, b0);
        computeB(g + 1, b1);
    }

    // row sums across the 16 lanes holding each row, one atomic per row
    #pragma unroll
    for (int s = 0; s < 4; ++s)
        #pragma unroll
        for (int r = 0; r < 4; ++r) {
            float v = accexp[s][r];
            v += __shfl_xor(v, 1);
            v += __shfl_xor(v, 2);
            v += __shfl_xor(v, 4);
            v += __shfl_xor(v, 8);
            if (c16 == 0)
                atomicAdd(&denom[R0 + s * 64 + wave * 16 + quad * 4 + r], v);
        }

    // last of 16 blocks per rtile: sum(log(denom[R0..R0+256))) / M -> out (+ pos term)
    __syncthreads();
    if (tid == 0) {
        __threadfence();                              // release our denom adds
        lastflag = (atomicAdd(&cnt[rtile], 1) == 15);
    }
    __syncthreads();
    if (lastflag) {
        __threadfence();                              // acquire others' denom adds
        float v = atomicAdd(&denom[R0 + tid], 0.0f);  // coherent read, 256 rows
        float p = __builtin_amdgcn_logf(v) * (LN2 / (float)M_);
        #pragma unroll
        for (int m = 1; m < 64; m <<= 1) p += __shfl_xor(p, m);
        if (lane == 0) red[wave] = p;
        __syncthreads();
        if (tid == 0) atomicAdd(out, red[0] + red[1] + red[2] + red[3]);
        if (rtile == 0) {                             // pos ready (knorm precedes)
            __syncthreads();                          // protect red reuse
            float sp = 0.0f;
            for (int i = tid; i < NS_; i += 256) sp += pos[i];
            #pragma unroll
            for (int m = 1; m < 64; m <<= 1) sp += __shfl_xor(sp, m);
            if (lane == 0) red[wave] = sp;
            __syncthreads();
            if (tid == 0)
                atomicAdd(out, (red[0] + red[1] + red[2] + red[3]) *
                               (-2.0f / (TEMP * (float)M_)));
        }
    }
}

extern "C" void kernel_launch(void* const* d_in, const int* in_sizes, int n_in,
                              void* d_out, int out_size, void* d_ws, size_t ws_size,
                              hipStream_t stream) {
    const float* z1 = (const float*)d_in[0];
    const float* z2 = (const float*)d_in[1];

    short* F     = (short*)d_ws;                                   // 4 MB
    float* denom = (float*)((char*)d_ws + (size_t)M_ * D_ * 2);    // 32 KB
    int*   cnt   = (int*)(denom + M_);                             // 128 B
    float* pos   = (float*)(cnt + 32);                             // 16 KB
    float* out   = (float*)d_out;

    knorm<<<NS_ / 4, 256, 0, stream>>>(z1, z2, F, pos, denom, cnt, out);
    kgemm<<<512, 256, 0, stream>>>(F, denom, cnt, pos, out);
}